// Round 1
// baseline (435.883 us; speedup 1.0000x reference)
//
#include <hip/hip_runtime.h>

#define IMG_H 320
#define IMG_W 320
#define NPIX (IMG_H * IMG_W)
#define HID 64
#define NS 32

// Transpose W2 (64x64 row-major, W2[k][j]) into W2T[j][k] so that for a fixed
// output neuron j the K-dim weights are contiguous -> compiler merges the
// wave-uniform reads into s_load_dwordx8/x16 on the scalar pipe.
__global__ __launch_bounds__(256) void transpose_w2(const float* __restrict__ W2,
                                                    float* __restrict__ W2T) {
    for (int i = threadIdx.x; i < HID * HID; i += 256) {
        int k = i >> 6, j = i & 63;
        W2T[j * HID + k] = W2[k * HID + j];
    }
}

__global__ __launch_bounds__(256) void nerf_kernel(
    const float* __restrict__ Kmat, const float* __restrict__ Twc,
    const float* __restrict__ aabb_min, const float* __restrict__ aabb_max,
    const float* __restrict__ W1, const float* __restrict__ b1,
    const float* __restrict__ W2T, const float* __restrict__ b2,
    const float* __restrict__ W3, const float* __restrict__ b3,
    float* __restrict__ out) {
    int gt = blockIdx.x * blockDim.x + threadIdx.x;
    int pix = gt >> 5;          // 32 sample-threads per pixel
    int s   = gt & 31;
    int lane = threadIdx.x & 31;
    int y = pix / IMG_W, x = pix - y * IMG_W;

    // ---- ray setup (uniform across the 32 lanes of a pixel; cheap) ----
    float fx = Kmat[0], cx = Kmat[2], fy = Kmat[4], cy = Kmat[5];
    float u = (float)x + 0.5f, v = (float)y + 0.5f;
    float dcx = (u - cx) / fx;
    float dcy = (v - cy) / fy;
    float dcz = 1.0f;
    float inorm = 1.0f / sqrtf(dcx * dcx + dcy * dcy + dcz * dcz);
    dcx *= inorm; dcy *= inorm; dcz *= inorm;

    // d_world = R @ d_cam,  R = Twc[:3,:3] (row-major 4x4)
    float dx = Twc[0] * dcx + Twc[1] * dcy + Twc[2]  * dcz;
    float dy = Twc[4] * dcx + Twc[5] * dcy + Twc[6]  * dcz;
    float dz = Twc[8] * dcx + Twc[9] * dcy + Twc[10] * dcz;
    float ox = Twc[3], oy = Twc[7], oz = Twc[11];

    float mnx = aabb_min[0], mny = aabb_min[1], mnz = aabb_min[2];
    float mxx = aabb_max[0], mxy = aabb_max[1], mxz = aabb_max[2];

    float ivx = 1.0f / dx, ivy = 1.0f / dy, ivz = 1.0f / dz;
    float t1x = (mnx - ox) * ivx, t2x = (mxx - ox) * ivx;
    float t1y = (mny - oy) * ivy, t2y = (mxy - oy) * ivy;
    float t1z = (mnz - oz) * ivz, t2z = (mxz - oz) * ivz;
    float tnear = fmaxf(fmaxf(fminf(t1x, t2x), fminf(t1y, t2y)), fminf(t1z, t2z));
    float tfar  = fminf(fminf(fmaxf(t1x, t2x), fmaxf(t1y, t2y)), fmaxf(t1z, t2z));
    bool hit = tnear < tfar;
    float tn = hit ? tnear : 0.0f;
    float tf = hit ? tfar  : 1.0f;

    float step = (tf - tn) * (1.0f / NS);
    float ts = tn + (tf - tn) * (((float)s + 0.5f) * (1.0f / NS));

    float px = ox + ts * dx, py = oy + ts * dy, pz = oz + ts * dz;
    float nx = (px - mnx) / (mxx - mnx) * 2.0f - 1.0f;
    float ny = (py - mny) / (mxy - mny) * 2.0f - 1.0f;
    float nz = (pz - mnz) / (mxz - mnz) * 2.0f - 1.0f;

    // ---- layer 1: 3 -> 64 (W1 is (3,64) row-major) ----
    float h[HID];
#pragma unroll
    for (int k = 0; k < HID; ++k) {
        float a = b1[k];
        a = fmaf(nx, W1[k], a);
        a = fmaf(ny, W1[HID + k], a);
        a = fmaf(nz, W1[2 * HID + k], a);
        h[k] = fmaxf(a, 0.0f);
    }

    // ---- layer 2 + layer 3 fused: for each hidden-2 neuron j, dot(h, W2T[j]),
    // relu, fold into the 4 raw outputs. Only h[64] + 4 accumulators live. ----
    float r0 = b3[0], r1 = b3[1], r2 = b3[2], r3 = b3[3];
#pragma unroll 1
    for (int j = 0; j < HID; ++j) {
        const float* wrow = W2T + j * HID;   // contiguous, wave-uniform -> s_load
        float acc = b2[j];
#pragma unroll
        for (int k = 0; k < HID; ++k) acc = fmaf(h[k], wrow[k], acc);
        acc = fmaxf(acc, 0.0f);
        const float* w3r = W3 + j * 4;
        r0 = fmaf(acc, w3r[0], r0);
        r1 = fmaf(acc, w3r[1], r1);
        r2 = fmaf(acc, w3r[2], r2);
        r3 = fmaf(acc, w3r[3], r3);
    }

    // ---- volume rendering ----
    float sigma = (r0 > 20.0f) ? r0 : log1pf(expf(r0));   // softplus
    float c0 = 1.0f / (1.0f + expf(-r1));
    float c1 = 1.0f / (1.0f + expf(-r2));
    float c2 = 1.0f / (1.0f + expf(-r3));
    float delta = (s == NS - 1) ? 0.5f * step : step;
    float sa = sigma * delta;

    // inclusive prefix sum of sa over the 32 lanes of this pixel
    float cum = sa;
#pragma unroll
    for (int off = 1; off < 32; off <<= 1) {
        float n = __shfl_up(cum, off, 32);
        cum += (lane >= off) ? n : 0.0f;
    }

    float Tprev = expf(-(cum - sa));
    float w = Tprev * (1.0f - expf(-sa));
    float rr = w * c0, rg = w * c1, rb = w * c2;
    float total = __shfl(cum, 31, 32);

    // sum rgb over the 32 lanes
#pragma unroll
    for (int off = 16; off; off >>= 1) {
        rr += __shfl_down(rr, off, 32);
        rg += __shfl_down(rg, off, 32);
        rb += __shfl_down(rb, off, 32);
    }

    if (lane == 0) {
        float alpha = 1.0f - expf(-total);
        if (!hit) { rr = 0.0f; rg = 0.0f; rb = 0.0f; alpha = 0.0f; }
        out[0 * NPIX + pix] = rr;
        out[1 * NPIX + pix] = rg;
        out[2 * NPIX + pix] = rb;
        out[3 * NPIX + pix] = alpha;
    }
}

extern "C" void kernel_launch(void* const* d_in, const int* in_sizes, int n_in,
                              void* d_out, int out_size, void* d_ws, size_t ws_size,
                              hipStream_t stream) {
    const float* Kmat = (const float*)d_in[0];
    const float* Twc  = (const float*)d_in[1];
    const float* amn  = (const float*)d_in[2];
    const float* amx  = (const float*)d_in[3];
    const float* W1   = (const float*)d_in[4];
    const float* b1   = (const float*)d_in[5];
    const float* W2   = (const float*)d_in[6];
    const float* b2   = (const float*)d_in[7];
    const float* W3   = (const float*)d_in[8];
    const float* b3   = (const float*)d_in[9];
    float* out = (float*)d_out;
    float* W2T = (float*)d_ws;   // 64*64*4 = 16 KB scratch

    transpose_w2<<<1, 256, 0, stream>>>(W2, W2T);

    int total_threads = NPIX * NS;           // 3,276,800
    int blocks = total_threads / 256;        // 12,800 exactly
    nerf_kernel<<<blocks, 256, 0, stream>>>(Kmat, Twc, amn, amx, W1, b1, W2T, b2,
                                            W3, b3, out);
}

// Round 2
// 412.025 us; speedup vs baseline: 1.0579x; 1.0579x over previous
//
#include <hip/hip_runtime.h>

#define IMG_H 320
#define IMG_W 320
#define NPIX (IMG_H * IMG_W)
#define HID 64
#define NS 32

// Transpose W2 (64x64 row-major, W2[k][j]) into W2T[j][k] so that for a fixed
// output neuron j the K-dim weights are contiguous -> compiler merges the
// wave-uniform reads into s_load_dwordx16 on the scalar pipe.
__global__ __launch_bounds__(256) void transpose_w2(const float* __restrict__ W2,
                                                    float* __restrict__ W2T) {
    for (int i = threadIdx.x; i < HID * HID; i += 256) {
        int k = i >> 6, j = i & 63;
        W2T[j * HID + k] = W2[k * HID + j];
    }
}

// __launch_bounds__(256, 2): min 2 workgroups/CU -> VGPR cap 256/wave.
// Without this the compiler targets high occupancy, caps arch-VGPRs at ~40,
// and shuffles h[64] through AGPRs (v_accvgpr_read per use = 2x VALU ops per
// FMA -> measured 40% FMA density in round 1). h[64]+working set ~110 VGPRs
// fits under the 256 cap; 2 waves/SIMD is plenty for a VALU-issue-bound body.
__global__ __launch_bounds__(256, 2) void nerf_kernel(
    const float* __restrict__ Kmat, const float* __restrict__ Twc,
    const float* __restrict__ aabb_min, const float* __restrict__ aabb_max,
    const float* __restrict__ W1, const float* __restrict__ b1,
    const float* __restrict__ W2T, const float* __restrict__ b2,
    const float* __restrict__ W3, const float* __restrict__ b3,
    float* __restrict__ out) {
    int gt = blockIdx.x * blockDim.x + threadIdx.x;
    int pix = gt >> 5;          // 32 sample-threads per pixel
    int s   = gt & 31;
    int lane = threadIdx.x & 31;
    int y = pix / IMG_W, x = pix - y * IMG_W;

    // ---- ray setup ----
    float fx = Kmat[0], cx = Kmat[2], fy = Kmat[4], cy = Kmat[5];
    float u = (float)x + 0.5f, v = (float)y + 0.5f;
    float dcx = (u - cx) / fx;
    float dcy = (v - cy) / fy;
    float dcz = 1.0f;
    float inorm = 1.0f / sqrtf(dcx * dcx + dcy * dcy + dcz * dcz);
    dcx *= inorm; dcy *= inorm; dcz *= inorm;

    // d_world = R @ d_cam,  R = Twc[:3,:3] (row-major 4x4)
    float dx = Twc[0] * dcx + Twc[1] * dcy + Twc[2]  * dcz;
    float dy = Twc[4] * dcx + Twc[5] * dcy + Twc[6]  * dcz;
    float dz = Twc[8] * dcx + Twc[9] * dcy + Twc[10] * dcz;
    float ox = Twc[3], oy = Twc[7], oz = Twc[11];

    float mnx = aabb_min[0], mny = aabb_min[1], mnz = aabb_min[2];
    float mxx = aabb_max[0], mxy = aabb_max[1], mxz = aabb_max[2];

    float ivx = 1.0f / dx, ivy = 1.0f / dy, ivz = 1.0f / dz;
    float t1x = (mnx - ox) * ivx, t2x = (mxx - ox) * ivx;
    float t1y = (mny - oy) * ivy, t2y = (mxy - oy) * ivy;
    float t1z = (mnz - oz) * ivz, t2z = (mxz - oz) * ivz;
    float tnear = fmaxf(fmaxf(fminf(t1x, t2x), fminf(t1y, t2y)), fminf(t1z, t2z));
    float tfar  = fminf(fminf(fmaxf(t1x, t2x), fmaxf(t1y, t2y)), fmaxf(t1z, t2z));
    bool hit = tnear < tfar;
    float tn = hit ? tnear : 0.0f;
    float tf = hit ? tfar  : 1.0f;

    float step = (tf - tn) * (1.0f / NS);
    float ts = tn + (tf - tn) * (((float)s + 0.5f) * (1.0f / NS));

    float px = ox + ts * dx, py = oy + ts * dy, pz = oz + ts * dz;
    float nx = (px - mnx) / (mxx - mnx) * 2.0f - 1.0f;
    float ny = (py - mny) / (mxy - mny) * 2.0f - 1.0f;
    float nz = (pz - mnz) / (mxz - mnz) * 2.0f - 1.0f;

    // ---- layer 1: 3 -> 64 (W1 is (3,64) row-major) ----
    float h[HID];
#pragma unroll
    for (int k = 0; k < HID; ++k) {
        float a = b1[k];
        a = fmaf(nx, W1[k], a);
        a = fmaf(ny, W1[HID + k], a);
        a = fmaf(nz, W1[2 * HID + k], a);
        h[k] = fmaxf(a, 0.0f);
    }

    // ---- layer 2 + layer 3 fused ----
    // 4 independent FMA chains per j (dep latency 4cy x 16 deep = 64cy < the
    // 128cy of issue) so 2 waves/SIMD keep the VALU saturated.
    float r0 = b3[0], r1 = b3[1], r2 = b3[2], r3 = b3[3];
#pragma unroll 1
    for (int j = 0; j < HID; ++j) {
        const float* wrow = W2T + j * HID;   // contiguous, wave-uniform -> s_load
        float a0 = b2[j], a1 = 0.0f, a2 = 0.0f, a3 = 0.0f;
#pragma unroll
        for (int k = 0; k < HID; k += 4) {
            a0 = fmaf(h[k + 0], wrow[k + 0], a0);
            a1 = fmaf(h[k + 1], wrow[k + 1], a1);
            a2 = fmaf(h[k + 2], wrow[k + 2], a2);
            a3 = fmaf(h[k + 3], wrow[k + 3], a3);
        }
        float acc = fmaxf((a0 + a1) + (a2 + a3), 0.0f);
        const float* w3r = W3 + j * 4;
        r0 = fmaf(acc, w3r[0], r0);
        r1 = fmaf(acc, w3r[1], r1);
        r2 = fmaf(acc, w3r[2], r2);
        r3 = fmaf(acc, w3r[3], r3);
    }

    // ---- volume rendering ----
    float sigma = (r0 > 20.0f) ? r0 : log1pf(expf(r0));   // softplus
    float c0 = 1.0f / (1.0f + expf(-r1));
    float c1 = 1.0f / (1.0f + expf(-r2));
    float c2 = 1.0f / (1.0f + expf(-r3));
    float delta = (s == NS - 1) ? 0.5f * step : step;
    float sa = sigma * delta;

    // inclusive prefix sum of sa over the 32 lanes of this pixel
    float cum = sa;
#pragma unroll
    for (int off = 1; off < 32; off <<= 1) {
        float n = __shfl_up(cum, off, 32);
        cum += (lane >= off) ? n : 0.0f;
    }

    float Tprev = expf(-(cum - sa));
    float w = Tprev * (1.0f - expf(-sa));
    float rr = w * c0, rg = w * c1, rb = w * c2;
    float total = __shfl(cum, 31, 32);

    // sum rgb over the 32 lanes
#pragma unroll
    for (int off = 16; off; off >>= 1) {
        rr += __shfl_down(rr, off, 32);
        rg += __shfl_down(rg, off, 32);
        rb += __shfl_down(rb, off, 32);
    }

    if (lane == 0) {
        float alpha = 1.0f - expf(-total);
        if (!hit) { rr = 0.0f; rg = 0.0f; rb = 0.0f; alpha = 0.0f; }
        out[0 * NPIX + pix] = rr;
        out[1 * NPIX + pix] = rg;
        out[2 * NPIX + pix] = rb;
        out[3 * NPIX + pix] = alpha;
    }
}

extern "C" void kernel_launch(void* const* d_in, const int* in_sizes, int n_in,
                              void* d_out, int out_size, void* d_ws, size_t ws_size,
                              hipStream_t stream) {
    const float* Kmat = (const float*)d_in[0];
    const float* Twc  = (const float*)d_in[1];
    const float* amn  = (const float*)d_in[2];
    const float* amx  = (const float*)d_in[3];
    const float* W1   = (const float*)d_in[4];
    const float* b1   = (const float*)d_in[5];
    const float* W2   = (const float*)d_in[6];
    const float* b2   = (const float*)d_in[7];
    const float* W3   = (const float*)d_in[8];
    const float* b3   = (const float*)d_in[9];
    float* out = (float*)d_out;
    float* W2T = (float*)d_ws;   // 64*64*4 = 16 KB scratch

    transpose_w2<<<1, 256, 0, stream>>>(W2, W2T);

    int total_threads = NPIX * NS;           // 3,276,800
    int blocks = total_threads / 256;        // 12,800 exactly
    nerf_kernel<<<blocks, 256, 0, stream>>>(Kmat, Twc, amn, amx, W1, b1, W2T, b2,
                                            W3, b3, out);
}

// Round 3
// 129.764 us; speedup vs baseline: 3.3590x; 3.1752x over previous
//
#include <hip/hip_runtime.h>
#include <hip/hip_bf16.h>

#define IMG_H 320
#define IMG_W 320
#define NPIX (IMG_H * IMG_W)
#define HID 64
#define NS 32
#define ROWP 72   // h1 LDS row length in bf16 elems (144 B: 16B-aligned, bank-balanced)

typedef __attribute__((ext_vector_type(8))) short short8;   // 8 x bf16 (4 VGPR)
typedef __attribute__((ext_vector_type(4))) float float4v;  // MFMA acc

// prep: w2t[j*64+k] = bf16(W2[k][j])  (A-operand of swapped layer-2 GEMM)
__global__ __launch_bounds__(256) void prep_weights(const float* __restrict__ W2,
                                                    short* __restrict__ w2t) {
    for (int i = threadIdx.x; i < HID * HID; i += 256) {
        int j = i >> 6, k = i & 63;
        __hip_bfloat16 b = __float2bfloat16(W2[k * HID + j]);
        w2t[j * HID + k] = *reinterpret_cast<short*>(&b);
    }
}

__global__ __launch_bounds__(256, 2) void nerf_mfma(
    const float* __restrict__ Kmat, const float* __restrict__ Twc,
    const float* __restrict__ aabb_min, const float* __restrict__ aabb_max,
    const float* __restrict__ W1, const float* __restrict__ b1,
    const short* __restrict__ w2t, const float* __restrict__ b2,
    const float* __restrict__ W3, const float* __restrict__ b3,
    float* __restrict__ out) {
    __shared__ short h1s[256 * ROWP];      // 36 KB: per-sample h1 rows (bf16 bits)
    __shared__ float raw4[256][4];         // 4 KB: per-sample raw MLP outputs

    const int tid  = threadIdx.x;
    const int wave = tid >> 6;
    const int lane = tid & 63;
    const int l15  = lane & 15;            // MFMA col / A-row selector
    const int g    = lane >> 4;            // MFMA k-group selector

    const int sampleId = blockIdx.x * 256 + tid;
    const int pix = sampleId >> 5;
    const int s   = sampleId & 31;

    // ---------------- ray setup (per sample) ----------------
    int y = pix / IMG_W, x = pix - y * IMG_W;
    float fx = Kmat[0], cx = Kmat[2], fy = Kmat[4], cy = Kmat[5];
    float u = (float)x + 0.5f, v = (float)y + 0.5f;
    float dcx = (u - cx) / fx, dcy = (v - cy) / fy, dcz = 1.0f;
    float inorm = 1.0f / sqrtf(dcx * dcx + dcy * dcy + dcz * dcz);
    dcx *= inorm; dcy *= inorm; dcz *= inorm;
    float dx = Twc[0] * dcx + Twc[1] * dcy + Twc[2]  * dcz;
    float dy = Twc[4] * dcx + Twc[5] * dcy + Twc[6]  * dcz;
    float dz = Twc[8] * dcx + Twc[9] * dcy + Twc[10] * dcz;
    float ox = Twc[3], oy = Twc[7], oz = Twc[11];

    float mnx = aabb_min[0], mny = aabb_min[1], mnz = aabb_min[2];
    float mxx = aabb_max[0], mxy = aabb_max[1], mxz = aabb_max[2];
    float ivx = 1.0f / dx, ivy = 1.0f / dy, ivz = 1.0f / dz;
    float t1x = (mnx - ox) * ivx, t2x = (mxx - ox) * ivx;
    float t1y = (mny - oy) * ivy, t2y = (mxy - oy) * ivy;
    float t1z = (mnz - oz) * ivz, t2z = (mxz - oz) * ivz;
    float tnear = fmaxf(fmaxf(fminf(t1x, t2x), fminf(t1y, t2y)), fminf(t1z, t2z));
    float tfar  = fminf(fminf(fmaxf(t1x, t2x), fmaxf(t1y, t2y)), fmaxf(t1z, t2z));
    bool hit = tnear < tfar;
    float tn = hit ? tnear : 0.0f;
    float tf = hit ? tfar  : 1.0f;
    float step = (tf - tn) * (1.0f / NS);
    float ts = tn + (tf - tn) * (((float)s + 0.5f) * (1.0f / NS));
    float px = ox + ts * dx, py = oy + ts * dy, pz = oz + ts * dz;
    float nx = (px - mnx) / (mxx - mnx) * 2.0f - 1.0f;
    float ny = (py - mny) / (mxy - mny) * 2.0f - 1.0f;
    float nz = (pz - mnz) / (mxz - mnz) * 2.0f - 1.0f;

    // ---------------- layer 1 on VALU: 3 -> 64, write bf16 row to LDS --------
    {
        short* row = h1s + tid * ROWP;
#pragma unroll
        for (int k8 = 0; k8 < HID; k8 += 8) {
            short8 pk;
#pragma unroll
            for (int e = 0; e < 8; ++e) {
                int k = k8 + e;
                float a = b1[k];
                a = fmaf(nx, W1[k], a);
                a = fmaf(ny, W1[HID + k], a);
                a = fmaf(nz, W1[2 * HID + k], a);
                a = fmaxf(a, 0.0f);
                __hip_bfloat16 hb = __float2bfloat16(a);
                pk[e] = *reinterpret_cast<short*>(&hb);
            }
            *reinterpret_cast<short8*>(row + k8) = pk;   // ds_write_b128
        }
    }
    __syncthreads();

    // ---------------- layer 2 on MFMA (swapped): D[j][s] = W2^T x H1^T -------
    // A-frag: lane holds A[j = 16*mt + l15][k = 32*T + 8*g + e]  (weights, global, hoisted)
    short8 afrag[4][2];
#pragma unroll
    for (int mt = 0; mt < 4; ++mt)
#pragma unroll
        for (int T = 0; T < 2; ++T)
            afrag[mt][T] = *reinterpret_cast<const short8*>(
                w2t + (16 * mt + l15) * HID + 32 * T + 8 * g);

    float4v acc[4][4];   // [mt(j-tile)][nt(sample-tile)]
#pragma unroll
    for (int mt = 0; mt < 4; ++mt)
#pragma unroll
        for (int nt = 0; nt < 4; ++nt) acc[mt][nt] = (float4v){0.f, 0.f, 0.f, 0.f};

    const short* bbase = h1s + (wave * 64) * ROWP;
#pragma unroll
    for (int nt = 0; nt < 4; ++nt) {
#pragma unroll
        for (int T = 0; T < 2; ++T) {
            // B-frag: lane holds B[k = 32*T + 8*g + e][s = 16*nt + l15] = h1[s][k]
            short8 bfrag = *reinterpret_cast<const short8*>(
                bbase + (16 * nt + l15) * ROWP + 32 * T + 8 * g);
#pragma unroll
            for (int mt = 0; mt < 4; ++mt)
                acc[mt][nt] = __builtin_amdgcn_mfma_f32_16x16x32_bf16(
                    afrag[mt][T], bfrag, acc[mt][nt], 0, 0, 0);
        }
    }

    // ---------------- layer 3 on VALU from registers -------------------------
    // D layout (verified): lane reg r holds D[j = 16*mt + 4*g + r][s = 16*nt + l15]
    float partial[4][4];   // [nt][c]
#pragma unroll
    for (int nt = 0; nt < 4; ++nt)
#pragma unroll
        for (int c = 0; c < 4; ++c) partial[nt][c] = 0.0f;

#pragma unroll
    for (int mt = 0; mt < 4; ++mt) {
        int j0 = 16 * mt + 4 * g;
        float4v bb = *reinterpret_cast<const float4v*>(b2 + j0);   // 16B aligned
        float4v w3r[4];
#pragma unroll
        for (int r = 0; r < 4; ++r)
            w3r[r] = *reinterpret_cast<const float4v*>(W3 + (j0 + r) * 4);
#pragma unroll
        for (int nt = 0; nt < 4; ++nt) {
#pragma unroll
            for (int r = 0; r < 4; ++r) {
                float hv = fmaxf(acc[mt][nt][r] + bb[r], 0.0f);
                partial[nt][0] = fmaf(hv, w3r[r][0], partial[nt][0]);
                partial[nt][1] = fmaf(hv, w3r[r][1], partial[nt][1]);
                partial[nt][2] = fmaf(hv, w3r[r][2], partial[nt][2]);
                partial[nt][3] = fmaf(hv, w3r[r][3], partial[nt][3]);
            }
        }
    }
    // reduce over the 4 lane-groups (each holds 16 of the 64 j's for its sample)
#pragma unroll
    for (int nt = 0; nt < 4; ++nt)
#pragma unroll
        for (int c = 0; c < 4; ++c) {
            float vsum = partial[nt][c];
            vsum += __shfl_xor(vsum, 16, 64);
            vsum += __shfl_xor(vsum, 32, 64);
            partial[nt][c] = vsum;
        }
    // lane-group 0 writes raw outputs (+b3) for samples 16*nt + l15
    if (g == 0) {
#pragma unroll
        for (int nt = 0; nt < 4; ++nt) {
            float4v r;
            r[0] = partial[nt][0] + b3[0];
            r[1] = partial[nt][1] + b3[1];
            r[2] = partial[nt][2] + b3[2];
            r[3] = partial[nt][3] + b3[3];
            *reinterpret_cast<float4v*>(&raw4[wave * 64 + 16 * nt + l15][0]) = r;
        }
    }
    __syncthreads();

    // ---------------- volume rendering (per sample, verified code) -----------
    float4v raw = *reinterpret_cast<const float4v*>(&raw4[tid][0]);
    float r0 = raw[0], r1 = raw[1], r2 = raw[2], r3 = raw[3];

    float sigma = (r0 > 20.0f) ? r0 : log1pf(expf(r0));
    float c0 = 1.0f / (1.0f + expf(-r1));
    float c1 = 1.0f / (1.0f + expf(-r2));
    float c2 = 1.0f / (1.0f + expf(-r3));
    float delta = (s == NS - 1) ? 0.5f * step : step;
    float sa = sigma * delta;

    int rlane = tid & 31;
    float cum = sa;
#pragma unroll
    for (int off = 1; off < 32; off <<= 1) {
        float n = __shfl_up(cum, off, 32);
        cum += (rlane >= off) ? n : 0.0f;
    }
    float Tprev = expf(-(cum - sa));
    float w = Tprev * (1.0f - expf(-sa));
    float rr = w * c0, rg = w * c1, rb = w * c2;
    float total = __shfl(cum, 31, 32);
#pragma unroll
    for (int off = 16; off; off >>= 1) {
        rr += __shfl_down(rr, off, 32);
        rg += __shfl_down(rg, off, 32);
        rb += __shfl_down(rb, off, 32);
    }
    if (rlane == 0) {
        float alpha = 1.0f - expf(-total);
        if (!hit) { rr = 0.0f; rg = 0.0f; rb = 0.0f; alpha = 0.0f; }
        out[0 * NPIX + pix] = rr;
        out[1 * NPIX + pix] = rg;
        out[2 * NPIX + pix] = rb;
        out[3 * NPIX + pix] = alpha;
    }
}

extern "C" void kernel_launch(void* const* d_in, const int* in_sizes, int n_in,
                              void* d_out, int out_size, void* d_ws, size_t ws_size,
                              hipStream_t stream) {
    const float* Kmat = (const float*)d_in[0];
    const float* Twc  = (const float*)d_in[1];
    const float* amn  = (const float*)d_in[2];
    const float* amx  = (const float*)d_in[3];
    const float* W1   = (const float*)d_in[4];
    const float* b1   = (const float*)d_in[5];
    const float* W2   = (const float*)d_in[6];
    const float* b2   = (const float*)d_in[7];
    const float* W3   = (const float*)d_in[8];
    const float* b3   = (const float*)d_in[9];
    float* out = (float*)d_out;
    short* w2t = (short*)d_ws;   // 64*64*2 = 8 KB bf16 scratch

    prep_weights<<<1, 256, 0, stream>>>(W2, w2t);

    int blocks = NPIX * NS / 256;   // 12,800
    nerf_mfma<<<blocks, 256, 0, stream>>>(Kmat, Twc, amn, amx, W1, b1, w2t, b2,
                                          W3, b3, out);
}

// Round 4
// 102.447 us; speedup vs baseline: 4.2547x; 1.2666x over previous
//
#include <hip/hip_runtime.h>
#include <hip/hip_bf16.h>

#define IMG_H 320
#define IMG_W 320
#define NPIX (IMG_H * IMG_W)
#define HID 64
#define NS 32
#define ROWP 72   // padded LDS h-row length in shorts (144 B -> free 2-way conflicts)

typedef __attribute__((ext_vector_type(8))) short short8;   // bf16 x8 (4 VGPR)
typedef __attribute__((ext_vector_type(4))) float float4v;
typedef __attribute__((ext_vector_type(4))) int   int4v;

// workspace layout (shorts): w2t[4096] | w1t[2048] | w3t[1024]  then (floats) b3pad[16]
#define W2T_OFF 0
#define W1T_OFF 4096
#define W3T_OFF (4096 + 2048)
#define B3P_FLT ((4096 + 2048 + 1024) / 2)   // float index into (float*)ws = 3584

__device__ __forceinline__ unsigned f2bf(float f) {
    __hip_bfloat16 b = __float2bfloat16(f);
    return (unsigned)*reinterpret_cast<unsigned short*>(&b);
}

// Build bf16 operand tables:
//  w1t[j][k](64x32): k<3 -> W1[k][j], k==3 -> b1[j] (bias row, B supplies 1.0), else 0
//  w2t[j][k](64x64): W2[k][j]
//  w3t[c][j](16x64): c<4 -> W3[j][c], else 0
//  b3pad[16]: b3 zero-extended (MFMA C-init for layer 3)
__global__ __launch_bounds__(256) void prep(const float* __restrict__ W1,
                                            const float* __restrict__ b1,
                                            const float* __restrict__ W2,
                                            const float* __restrict__ W3,
                                            const float* __restrict__ b3,
                                            short* __restrict__ wsS) {
    int t = threadIdx.x;
    float* wsF = reinterpret_cast<float*>(wsS);
    for (int i = t; i < 4096; i += 256) {
        int j = i >> 6, k = i & 63;
        wsS[W2T_OFF + i] = (short)f2bf(W2[k * HID + j]);
    }
    for (int i = t; i < 2048; i += 256) {
        int j = i >> 5, k = i & 31;
        float v = (k < 3) ? W1[k * HID + j] : ((k == 3) ? b1[j] : 0.0f);
        wsS[W1T_OFF + i] = (short)f2bf(v);
    }
    for (int i = t; i < 1024; i += 256) {
        int c = i >> 6, j = i & 63;
        float v = (c < 4) ? W3[j * 4 + c] : 0.0f;
        wsS[W3T_OFF + i] = (short)f2bf(v);
    }
    if (t < 16) wsF[B3P_FLT + t] = (t < 4) ? b3[t] : 0.0f;
}

__global__ __launch_bounds__(256, 2) void nerf_mfma3(
    const float* __restrict__ Kmat, const float* __restrict__ Twc,
    const float* __restrict__ aabb_min, const float* __restrict__ aabb_max,
    const short* __restrict__ ws, const float* __restrict__ b2,
    float* __restrict__ out) {
    // per-wave h buffer (h1 then h2, reused) + per-sample raw outputs.
    // ALL LDS traffic is wave-local: no __syncthreads anywhere; per-wave
    // in-order DS completion + lgkmcnt(0) fences provide the ordering.
    __shared__ short hbuf[4][64 * ROWP];   // 36 KB
    __shared__ float raw4[256][4];         // 4 KB

    const int tid  = threadIdx.x;
    const int wave = tid >> 6;
    const int lane = tid & 63;
    const int l15  = lane & 15;
    const int g    = lane >> 4;

    const short* w2t = ws + W2T_OFF;
    const short* w1t = ws + W1T_OFF;
    const short* w3t = ws + W3T_OFF;
    const float* b3p = reinterpret_cast<const float*>(ws) + B3P_FLT;
    short* hrow = hbuf[wave];

    const int sampleId = blockIdx.x * 256 + tid;
    const int pix = sampleId >> 5;
    const int s   = sampleId & 31;

    // ---------------- ray setup (per sample) ----------------
    int y = pix / IMG_W, x = pix - y * IMG_W;
    float fx = Kmat[0], cx = Kmat[2], fy = Kmat[4], cy = Kmat[5];
    float u = (float)x + 0.5f, v = (float)y + 0.5f;
    float dcx = (u - cx) / fx, dcy = (v - cy) / fy, dcz = 1.0f;
    float inorm = rsqrtf(dcx * dcx + dcy * dcy + dcz * dcz);
    dcx *= inorm; dcy *= inorm; dcz *= inorm;
    float dx = Twc[0] * dcx + Twc[1] * dcy + Twc[2]  * dcz;
    float dy = Twc[4] * dcx + Twc[5] * dcy + Twc[6]  * dcz;
    float dz = Twc[8] * dcx + Twc[9] * dcy + Twc[10] * dcz;
    float ox = Twc[3], oy = Twc[7], oz = Twc[11];

    float mnx = aabb_min[0], mny = aabb_min[1], mnz = aabb_min[2];
    float mxx = aabb_max[0], mxy = aabb_max[1], mxz = aabb_max[2];
    float ivx = 1.0f / dx, ivy = 1.0f / dy, ivz = 1.0f / dz;   // IEEE: hit matches ref
    float t1x = (mnx - ox) * ivx, t2x = (mxx - ox) * ivx;
    float t1y = (mny - oy) * ivy, t2y = (mxy - oy) * ivy;
    float t1z = (mnz - oz) * ivz, t2z = (mxz - oz) * ivz;
    float tnear = fmaxf(fmaxf(fminf(t1x, t2x), fminf(t1y, t2y)), fminf(t1z, t2z));
    float tfar  = fminf(fminf(fmaxf(t1x, t2x), fmaxf(t1y, t2y)), fmaxf(t1z, t2z));
    bool hit = tnear < tfar;
    float tn = hit ? tnear : 0.0f;
    float tf = hit ? tfar  : 1.0f;
    float step = (tf - tn) * (1.0f / NS);
    float ts = tn + (tf - tn) * (((float)s + 0.5f) * (1.0f / NS));
    float px = ox + ts * dx, py = oy + ts * dy, pz = oz + ts * dz;
    float nx = (px - mnx) / (mxx - mnx) * 2.0f - 1.0f;
    float ny = (py - mny) / (mxy - mny) * 2.0f - 1.0f;
    float nz = (pz - mnz) / (mxz - mnz) * 2.0f - 1.0f;

    // own sample's (x,y,z,1) packed as 4 bf16 in 2 dwords (shuffle currency)
    unsigned pd0 = f2bf(nx) | (f2bf(ny) << 16);
    unsigned pd1 = f2bf(nz) | (0x3F80u << 16);

    // ---------------- layer 1 on MFMA: D1[j][s] = W1T(+b1 row) x [xyz;1] -----
    short8 a1[4];
#pragma unroll
    for (int mt = 0; mt < 4; ++mt)
        a1[mt] = *reinterpret_cast<const short8*>(w1t + (16 * mt + l15) * 32 + 8 * g);

    float4v acc1[4][4];
#pragma unroll
    for (int mt = 0; mt < 4; ++mt)
#pragma unroll
        for (int nt = 0; nt < 4; ++nt) acc1[mt][nt] = (float4v){0.f, 0.f, 0.f, 0.f};

#pragma unroll
    for (int nt = 0; nt < 4; ++nt) {
        int u0 = __shfl((int)pd0, 16 * nt + l15, 64);
        int u1 = __shfl((int)pd1, 16 * nt + l15, 64);
        int4v bi;
        bi[0] = (g == 0) ? u0 : 0;   // k=0..3 live only in lane-group 0
        bi[1] = (g == 0) ? u1 : 0;
        bi[2] = 0; bi[3] = 0;
        short8 bf = *reinterpret_cast<short8*>(&bi);
#pragma unroll
        for (int mt = 0; mt < 4; ++mt)
            acc1[mt][nt] = __builtin_amdgcn_mfma_f32_16x16x32_bf16(a1[mt], bf,
                                                                   acc1[mt][nt], 0, 0, 0);
    }

    // relu + bf16 pack + store h1 rows [s][j] (wave-local)
#pragma unroll
    for (int mt = 0; mt < 4; ++mt)
#pragma unroll
        for (int nt = 0; nt < 4; ++nt) {
            float4v a = acc1[mt][nt];
            uint2 pv;
            pv.x = f2bf(fmaxf(a[0], 0.f)) | (f2bf(fmaxf(a[1], 0.f)) << 16);
            pv.y = f2bf(fmaxf(a[2], 0.f)) | (f2bf(fmaxf(a[3], 0.f)) << 16);
            *reinterpret_cast<uint2*>(hrow + (16 * nt + l15) * ROWP + 16 * mt + 4 * g) = pv;
        }
    asm volatile("s_waitcnt lgkmcnt(0)" ::: "memory");

    // ---------------- layer 2 on MFMA: D2[j][s] = W2T x h1, C-init = b2 ------
    short8 a2[4][2];
#pragma unroll
    for (int mt = 0; mt < 4; ++mt)
#pragma unroll
        for (int T = 0; T < 2; ++T)
            a2[mt][T] = *reinterpret_cast<const short8*>(
                w2t + (16 * mt + l15) * HID + 32 * T + 8 * g);

    float4v acc2[4][4];
#pragma unroll
    for (int mt = 0; mt < 4; ++mt) {
        float4v bb = *reinterpret_cast<const float4v*>(b2 + 16 * mt + 4 * g);
#pragma unroll
        for (int nt = 0; nt < 4; ++nt) acc2[mt][nt] = bb;
    }

#pragma unroll
    for (int nt = 0; nt < 4; ++nt) {
        const short* rb = hrow + (16 * nt + l15) * ROWP + 8 * g;
        short8 bf0 = *reinterpret_cast<const short8*>(rb);
        short8 bf1 = *reinterpret_cast<const short8*>(rb + 32);
#pragma unroll
        for (int mt = 0; mt < 4; ++mt)
            acc2[mt][nt] = __builtin_amdgcn_mfma_f32_16x16x32_bf16(a2[mt][0], bf0,
                                                                   acc2[mt][nt], 0, 0, 0);
#pragma unroll
        for (int mt = 0; mt < 4; ++mt)
            acc2[mt][nt] = __builtin_amdgcn_mfma_f32_16x16x32_bf16(a2[mt][1], bf1,
                                                                   acc2[mt][nt], 0, 0, 0);
    }
    asm volatile("s_waitcnt lgkmcnt(0)" ::: "memory");   // all h1 reads landed

    // relu + pack + store h2 into the SAME wave-local buffer
#pragma unroll
    for (int mt = 0; mt < 4; ++mt)
#pragma unroll
        for (int nt = 0; nt < 4; ++nt) {
            float4v a = acc2[mt][nt];
            uint2 pv;
            pv.x = f2bf(fmaxf(a[0], 0.f)) | (f2bf(fmaxf(a[1], 0.f)) << 16);
            pv.y = f2bf(fmaxf(a[2], 0.f)) | (f2bf(fmaxf(a[3], 0.f)) << 16);
            *reinterpret_cast<uint2*>(hrow + (16 * nt + l15) * ROWP + 16 * mt + 4 * g) = pv;
        }
    asm volatile("s_waitcnt lgkmcnt(0)" ::: "memory");

    // ---------------- layer 3 on MFMA: D3[c][s] = W3T x h2, C-init = b3pad ---
    short8 a30 = *reinterpret_cast<const short8*>(w3t + l15 * HID + 8 * g);
    short8 a31 = *reinterpret_cast<const short8*>(w3t + l15 * HID + 32 + 8 * g);
    float4v ci = *reinterpret_cast<const float4v*>(b3p + 4 * g);
#pragma unroll
    for (int nt = 0; nt < 4; ++nt) {
        const short* rb = hrow + (16 * nt + l15) * ROWP + 8 * g;
        short8 bf0 = *reinterpret_cast<const short8*>(rb);
        short8 bf1 = *reinterpret_cast<const short8*>(rb + 32);
        float4v dv = __builtin_amdgcn_mfma_f32_16x16x32_bf16(a30, bf0, ci, 0, 0, 0);
        dv = __builtin_amdgcn_mfma_f32_16x16x32_bf16(a31, bf1, dv, 0, 0, 0);
        if (g == 0)   // rows 0..3 = raw outputs of sample 16*nt+l15
            *reinterpret_cast<float4v*>(&raw4[wave * 64 + 16 * nt + l15][0]) = dv;
    }
    asm volatile("s_waitcnt lgkmcnt(0)" ::: "memory");

    // ---------------- volume rendering (per sample) ----------------
    float4v raw = *reinterpret_cast<const float4v*>(&raw4[tid][0]);
    float r0 = raw[0], r1 = raw[1], r2 = raw[2], r3 = raw[3];

    float sigma = (r0 > 20.0f) ? r0 : __logf(1.0f + __expf(r0));
    float c0 = __builtin_amdgcn_rcpf(1.0f + __expf(-r1));
    float c1 = __builtin_amdgcn_rcpf(1.0f + __expf(-r2));
    float c2 = __builtin_amdgcn_rcpf(1.0f + __expf(-r3));
    float delta = (s == NS - 1) ? 0.5f * step : step;
    float sa = sigma * delta;

    int rlane = tid & 31;
    float cum = sa;
#pragma unroll
    for (int off = 1; off < 32; off <<= 1) {
        float n = __shfl_up(cum, off, 32);
        cum += (rlane >= off) ? n : 0.0f;
    }
    float Tprev = __expf(-(cum - sa));
    float w = Tprev * (1.0f - __expf(-sa));
    float rr = w * c0, rg = w * c1, rb = w * c2;
    float total = __shfl(cum, 31, 32);
#pragma unroll
    for (int off = 16; off; off >>= 1) {
        rr += __shfl_down(rr, off, 32);
        rg += __shfl_down(rg, off, 32);
        rb += __shfl_down(rb, off, 32);
    }
    if (rlane == 0) {
        float alpha = 1.0f - __expf(-total);
        if (!hit) { rr = 0.0f; rg = 0.0f; rb = 0.0f; alpha = 0.0f; }
        out[0 * NPIX + pix] = rr;
        out[1 * NPIX + pix] = rg;
        out[2 * NPIX + pix] = rb;
        out[3 * NPIX + pix] = alpha;
    }
}

extern "C" void kernel_launch(void* const* d_in, const int* in_sizes, int n_in,
                              void* d_out, int out_size, void* d_ws, size_t ws_size,
                              hipStream_t stream) {
    const float* Kmat = (const float*)d_in[0];
    const float* Twc  = (const float*)d_in[1];
    const float* amn  = (const float*)d_in[2];
    const float* amx  = (const float*)d_in[3];
    const float* W1   = (const float*)d_in[4];
    const float* b1   = (const float*)d_in[5];
    const float* W2   = (const float*)d_in[6];
    const float* b2   = (const float*)d_in[7];
    const float* W3   = (const float*)d_in[8];
    const float* b3   = (const float*)d_in[9];
    float* out = (float*)d_out;
    short* ws  = (short*)d_ws;   // 14.4 KB used

    prep<<<1, 256, 0, stream>>>(W1, b1, W2, W3, b3, ws);

    int blocks = NPIX * NS / 256;   // 12,800
    nerf_mfma3<<<blocks, 256, 0, stream>>>(Kmat, Twc, amn, amx, ws, b2, out);
}

// Round 5
// 93.633 us; speedup vs baseline: 4.6552x; 1.0941x over previous
//
#include <hip/hip_runtime.h>
#include <hip/hip_bf16.h>

#define IMG_H 320
#define IMG_W 320
#define NPIX (IMG_H * IMG_W)
#define HID 64
#define NS 32

typedef __attribute__((ext_vector_type(8))) short short8;   // bf16 x8 (4 VGPR)
typedef __attribute__((ext_vector_type(4))) float float4v;
typedef __attribute__((ext_vector_type(4))) int   int4v;

// workspace layout (shorts): w2t[4096] | w1t[2048] | w3t[1024]  then (floats) b3pad[16]
#define W2T_OFF 0
#define W1T_OFF 4096
#define W3T_OFF (4096 + 2048)
#define B3P_FLT ((4096 + 2048 + 1024) / 2)

__device__ __forceinline__ unsigned f2bf(float f) {
    __hip_bfloat16 b = __float2bfloat16(f);
    return (unsigned)*reinterpret_cast<unsigned short*>(&b);
}

// DPP add helper: x + dpp_shifted(x), 0-fill for invalid lanes / unwritten rows.
template <int CTRL, int RMASK>
__device__ __forceinline__ float dppadd(float x) {
    int s = __builtin_amdgcn_update_dpp(0, __float_as_int(x), CTRL, RMASK, 0xF, true);
    return x + __int_as_float(s);
}
// inclusive prefix sum over each 32-lane half (pure VALU, no LDS)
__device__ __forceinline__ float scan32(float x) {
    x = dppadd<0x111, 0xF>(x);   // row_shr:1
    x = dppadd<0x112, 0xF>(x);   // row_shr:2
    x = dppadd<0x114, 0xF>(x);   // row_shr:4
    x = dppadd<0x118, 0xF>(x);   // row_shr:8  -> per-16 inclusive scan
    x = dppadd<0x142, 0xA>(x);   // row_bcast:15 into rows 1,3 -> 32-inclusive
    return x;
}

// Build bf16 operand tables:
//  w1t[j][k](64x32): k<3 -> W1[k][j], k==3 -> b1[j] (bias row, B supplies 1.0), else 0
//  w2t[j][k](64x64): W2[k][j]
//  w3t[c][j](16x64): c<4 -> W3[j][c], else 0
//  b3pad[16]: b3 zero-extended (MFMA C-init for layer 3)
__global__ __launch_bounds__(256) void prep(const float* __restrict__ W1,
                                            const float* __restrict__ b1,
                                            const float* __restrict__ W2,
                                            const float* __restrict__ W3,
                                            const float* __restrict__ b3,
                                            short* __restrict__ wsS) {
    int t = threadIdx.x;
    float* wsF = reinterpret_cast<float*>(wsS);
    for (int i = t; i < 4096; i += 256) {
        int j = i >> 6, k = i & 63;
        wsS[W2T_OFF + i] = (short)f2bf(W2[k * HID + j]);
    }
    for (int i = t; i < 2048; i += 256) {
        int j = i >> 5, k = i & 31;
        float v = (k < 3) ? W1[k * HID + j] : ((k == 3) ? b1[j] : 0.0f);
        wsS[W1T_OFF + i] = (short)f2bf(v);
    }
    for (int i = t; i < 1024; i += 256) {
        int c = i >> 6, j = i & 63;
        float v = (c < 4) ? W3[j * 4 + c] : 0.0f;
        wsS[W3T_OFF + i] = (short)f2bf(v);
    }
    if (t < 16) wsF[B3P_FLT + t] = (t < 4) ? b3[t] : 0.0f;
}

__global__ __launch_bounds__(256, 2) void nerf_mfma4(
    const float* __restrict__ Kmat, const float* __restrict__ Twc,
    const float* __restrict__ aabb_min, const float* __restrict__ aabb_max,
    const short* __restrict__ ws, const float* __restrict__ b2,
    float* __restrict__ out) {
    // Conflict-free transposed h layout (per wave, dwords):
    //   hb[ ((j>>3)*64 + s)*4 + ((j>>1)&3) ] = bf16 pair (h[j],h[j+1]) for sample s.
    // Stores: uint2 at q = 2*(g&1) (each bank gets min-rate traffic).
    // Reads:  ds_read_b128 of q=0..3 contiguous -> B-frag for k-block 32T+8g.
    __shared__ unsigned hbuf[4][2048];     // 32 KB
    __shared__ float raw4[256][4];         // 4 KB

    const int tid  = threadIdx.x;
    const int wave = tid >> 6;
    const int lane = tid & 63;
    const int l15  = lane & 15;
    const int g    = lane >> 4;

    const short* w2t = ws + W2T_OFF;
    const short* w1t = ws + W1T_OFF;
    const short* w3t = ws + W3T_OFF;
    const float* b3p = reinterpret_cast<const float*>(ws) + B3P_FLT;
    unsigned* hb = hbuf[wave];

    const int sampleId = blockIdx.x * 256 + tid;
    const int pix = sampleId >> 5;
    const int s   = sampleId & 31;

    // ---------------- ray setup (per sample; all divides -> v_rcp) ----------
    int y = pix / IMG_W, x = pix - y * IMG_W;
    float fx = Kmat[0], cx = Kmat[2], fy = Kmat[4], cy = Kmat[5];
    float u = (float)x + 0.5f, v = (float)y + 0.5f;
    float dcx = (u - cx) * __builtin_amdgcn_rcpf(fx);
    float dcy = (v - cy) * __builtin_amdgcn_rcpf(fy);
    float dcz = 1.0f;
    float inorm = rsqrtf(dcx * dcx + dcy * dcy + dcz * dcz);
    dcx *= inorm; dcy *= inorm; dcz *= inorm;
    float dx = Twc[0] * dcx + Twc[1] * dcy + Twc[2]  * dcz;
    float dy = Twc[4] * dcx + Twc[5] * dcy + Twc[6]  * dcz;
    float dz = Twc[8] * dcx + Twc[9] * dcy + Twc[10] * dcz;
    float ox = Twc[3], oy = Twc[7], oz = Twc[11];

    float mnx = aabb_min[0], mny = aabb_min[1], mnz = aabb_min[2];
    float mxx = aabb_max[0], mxy = aabb_max[1], mxz = aabb_max[2];
    float ivx = __builtin_amdgcn_rcpf(dx);
    float ivy = __builtin_amdgcn_rcpf(dy);
    float ivz = __builtin_amdgcn_rcpf(dz);
    float t1x = (mnx - ox) * ivx, t2x = (mxx - ox) * ivx;
    float t1y = (mny - oy) * ivy, t2y = (mxy - oy) * ivy;
    float t1z = (mnz - oz) * ivz, t2z = (mxz - oz) * ivz;
    float tnear = fmaxf(fmaxf(fminf(t1x, t2x), fminf(t1y, t2y)), fminf(t1z, t2z));
    float tfar  = fminf(fminf(fmaxf(t1x, t2x), fmaxf(t1y, t2y)), fmaxf(t1z, t2z));
    bool hit = tnear < tfar;
    float tn = hit ? tnear : 0.0f;
    float tf = hit ? tfar  : 1.0f;
    float step = (tf - tn) * (1.0f / NS);
    float ts = tn + (tf - tn) * (((float)s + 0.5f) * (1.0f / NS));
    float px = ox + ts * dx, py = oy + ts * dy, pz = oz + ts * dz;
    float iex = __builtin_amdgcn_rcpf(mxx - mnx);
    float iey = __builtin_amdgcn_rcpf(mxy - mny);
    float iez = __builtin_amdgcn_rcpf(mxz - mnz);
    float nx = fmaf(px - mnx, 2.0f * iex, -1.0f);
    float ny = fmaf(py - mny, 2.0f * iey, -1.0f);
    float nz = fmaf(pz - mnz, 2.0f * iez, -1.0f);

    // own sample's (x,y,z,1) packed as 4 bf16 in 2 dwords (shuffle currency)
    unsigned pd0 = f2bf(nx) | (f2bf(ny) << 16);
    unsigned pd1 = f2bf(nz) | (0x3F80u << 16);

    // ---------------- layer 1 on MFMA: D1[j][s] = W1T(+b1 row) x [xyz;1] -----
    short8 a1[4];
#pragma unroll
    for (int mt = 0; mt < 4; ++mt)
        a1[mt] = *reinterpret_cast<const short8*>(w1t + (16 * mt + l15) * 32 + 8 * g);

    float4v acc1[4][4];
#pragma unroll
    for (int mt = 0; mt < 4; ++mt)
#pragma unroll
        for (int nt = 0; nt < 4; ++nt) acc1[mt][nt] = (float4v){0.f, 0.f, 0.f, 0.f};

#pragma unroll
    for (int nt = 0; nt < 4; ++nt) {
        int u0 = __shfl((int)pd0, 16 * nt + l15, 64);
        int u1 = __shfl((int)pd1, 16 * nt + l15, 64);
        int4v bi;
        bi[0] = (g == 0) ? u0 : 0;   // k=0..3 live only in lane-group 0
        bi[1] = (g == 0) ? u1 : 0;
        bi[2] = 0; bi[3] = 0;
        short8 bf = *reinterpret_cast<short8*>(&bi);
#pragma unroll
        for (int mt = 0; mt < 4; ++mt)
            acc1[mt][nt] = __builtin_amdgcn_mfma_f32_16x16x32_bf16(a1[mt], bf,
                                                                   acc1[mt][nt], 0, 0, 0);
    }

    // relu + bf16 pack + transposed store (j-pair p = 8mt+2g+d -> b = 2mt+(g>>1),
    // q = (2g+d)&3; d=0,1 are q-consecutive -> one uint2 store)
    const int sstore = (g >> 1) * 64 * 4 + 2 * (g & 1);   // lane-dependent part
#pragma unroll
    for (int mt = 0; mt < 4; ++mt)
#pragma unroll
        for (int nt = 0; nt < 4; ++nt) {
            float4v a = acc1[mt][nt];
            uint2 pv;
            pv.x = f2bf(fmaxf(a[0], 0.f)) | (f2bf(fmaxf(a[1], 0.f)) << 16);
            pv.y = f2bf(fmaxf(a[2], 0.f)) | (f2bf(fmaxf(a[3], 0.f)) << 16);
            *reinterpret_cast<uint2*>(hb + (2 * mt * 64 + 16 * nt + l15) * 4 + sstore) = pv;
        }
    asm volatile("s_waitcnt lgkmcnt(0)" ::: "memory");
    __builtin_amdgcn_sched_barrier(0);

    // ---------------- layer 2 on MFMA: D2[j][s] = W2T x h1, C-init = b2 ------
    short8 a2[4][2];
#pragma unroll
    for (int mt = 0; mt < 4; ++mt)
#pragma unroll
        for (int T = 0; T < 2; ++T)
            a2[mt][T] = *reinterpret_cast<const short8*>(
                w2t + (16 * mt + l15) * HID + 32 * T + 8 * g);

    float4v acc2[4][4];
#pragma unroll
    for (int mt = 0; mt < 4; ++mt) {
        float4v bb = *reinterpret_cast<const float4v*>(b2 + 16 * mt + 4 * g);
#pragma unroll
        for (int nt = 0; nt < 4; ++nt) acc2[mt][nt] = bb;
    }

#pragma unroll
    for (int nt = 0; nt < 4; ++nt) {
        // B-frag: k-block 32T+8g, sample 16nt+l15 -> b128 of q=0..3
        short8 bf0 = *reinterpret_cast<const short8*>(hb + ((0 + g) * 64 + 16 * nt + l15) * 4);
        short8 bf1 = *reinterpret_cast<const short8*>(hb + ((4 + g) * 64 + 16 * nt + l15) * 4);
#pragma unroll
        for (int mt = 0; mt < 4; ++mt)
            acc2[mt][nt] = __builtin_amdgcn_mfma_f32_16x16x32_bf16(a2[mt][0], bf0,
                                                                   acc2[mt][nt], 0, 0, 0);
#pragma unroll
        for (int mt = 0; mt < 4; ++mt)
            acc2[mt][nt] = __builtin_amdgcn_mfma_f32_16x16x32_bf16(a2[mt][1], bf1,
                                                                   acc2[mt][nt], 0, 0, 0);
    }
    asm volatile("s_waitcnt lgkmcnt(0)" ::: "memory");   // all h1 reads drained
    __builtin_amdgcn_sched_barrier(0);

    // relu + pack + store h2 into the SAME wave-local buffer (same layout)
#pragma unroll
    for (int mt = 0; mt < 4; ++mt)
#pragma unroll
        for (int nt = 0; nt < 4; ++nt) {
            float4v a = acc2[mt][nt];
            uint2 pv;
            pv.x = f2bf(fmaxf(a[0], 0.f)) | (f2bf(fmaxf(a[1], 0.f)) << 16);
            pv.y = f2bf(fmaxf(a[2], 0.f)) | (f2bf(fmaxf(a[3], 0.f)) << 16);
            *reinterpret_cast<uint2*>(hb + (2 * mt * 64 + 16 * nt + l15) * 4 + sstore) = pv;
        }
    asm volatile("s_waitcnt lgkmcnt(0)" ::: "memory");
    __builtin_amdgcn_sched_barrier(0);

    // ---------------- layer 3 on MFMA: D3[c][s] = W3T x h2, C-init = b3pad ---
    short8 a30 = *reinterpret_cast<const short8*>(w3t + l15 * HID + 8 * g);
    short8 a31 = *reinterpret_cast<const short8*>(w3t + l15 * HID + 32 + 8 * g);
    float4v ci = *reinterpret_cast<const float4v*>(b3p + 4 * g);
#pragma unroll
    for (int nt = 0; nt < 4; ++nt) {
        short8 bf0 = *reinterpret_cast<const short8*>(hb + ((0 + g) * 64 + 16 * nt + l15) * 4);
        short8 bf1 = *reinterpret_cast<const short8*>(hb + ((4 + g) * 64 + 16 * nt + l15) * 4);
        float4v dv = __builtin_amdgcn_mfma_f32_16x16x32_bf16(a30, bf0, ci, 0, 0, 0);
        dv = __builtin_amdgcn_mfma_f32_16x16x32_bf16(a31, bf1, dv, 0, 0, 0);
        if (g == 0)   // rows 0..3 = raw outputs of sample 16*nt+l15
            *reinterpret_cast<float4v*>(&raw4[wave * 64 + 16 * nt + l15][0]) = dv;
    }
    asm volatile("s_waitcnt lgkmcnt(0)" ::: "memory");
    __builtin_amdgcn_sched_barrier(0);

    // ---------------- volume rendering (per sample; DPP scans, no LDS) -------
    float4v raw = *reinterpret_cast<const float4v*>(&raw4[tid][0]);
    float r0 = raw[0], r1 = raw[1], r2 = raw[2], r3 = raw[3];

    // branchless softplus: max(x,0) + log1p(exp(-|x|))
    float sigma = fmaxf(r0, 0.0f) + __logf(1.0f + __expf(-fabsf(r0)));
    float c0 = __builtin_amdgcn_rcpf(1.0f + __expf(-r1));
    float c1 = __builtin_amdgcn_rcpf(1.0f + __expf(-r2));
    float c2 = __builtin_amdgcn_rcpf(1.0f + __expf(-r3));
    float delta = (s == NS - 1) ? 0.5f * step : step;
    float sa = sigma * delta;

    float cum = scan32(sa);                    // inclusive scan per 32-lane half
    float Tprev = __expf(-(cum - sa));
    float w = Tprev * (1.0f - __expf(-sa));
    float rr = scan32(w * c0);                 // lane31 value = full sum
    float rg = scan32(w * c1);
    float rb = scan32(w * c2);

    if (s == NS - 1) {                         // lane 31/63: holds the totals
        float alpha = 1.0f - __expf(-cum);
        float o0 = rr, o1 = rg, o2 = rb;
        if (!hit) { o0 = 0.0f; o1 = 0.0f; o2 = 0.0f; alpha = 0.0f; }
        out[0 * NPIX + pix] = o0;
        out[1 * NPIX + pix] = o1;
        out[2 * NPIX + pix] = o2;
        out[3 * NPIX + pix] = alpha;
    }
}

extern "C" void kernel_launch(void* const* d_in, const int* in_sizes, int n_in,
                              void* d_out, int out_size, void* d_ws, size_t ws_size,
                              hipStream_t stream) {
    const float* Kmat = (const float*)d_in[0];
    const float* Twc  = (const float*)d_in[1];
    const float* amn  = (const float*)d_in[2];
    const float* amx  = (const float*)d_in[3];
    const float* W1   = (const float*)d_in[4];
    const float* b1   = (const float*)d_in[5];
    const float* W2   = (const float*)d_in[6];
    const float* b2   = (const float*)d_in[7];
    const float* W3   = (const float*)d_in[8];
    const float* b3   = (const float*)d_in[9];
    float* out = (float*)d_out;
    short* ws  = (short*)d_ws;   // 14.4 KB used

    prep<<<1, 256, 0, stream>>>(W1, b1, W2, W3, b3, ws);

    int blocks = NPIX * NS / 256;   // 12,800
    nerf_mfma4<<<blocks, 256, 0, stream>>>(Kmat, Twc, amn, amx, ws, b2, out);
}